// Round 1
// baseline (162.323 us; speedup 1.0000x reference)
//
#include <hip/hip_runtime.h>

#define R 4
#define NTHREADS 256

// LDS layout (floats):
// W0 [0,84)   b0 [84,96)
// W1 [96,240) b1 [240,252)
// W2 [252,396) b2 [396,408)
// W3 [408,552) b3 [552,564)
// W4 [564,708) b4 [708,720)
// W5 [720,792) b5 [792,798)
// W6 [798,804) b6 [804,805)

__global__ __launch_bounds__(NTHREADS) void mlp_kernel(
    const float* __restrict__ in,
    const float* __restrict__ W0, const float* __restrict__ b0,
    const float* __restrict__ W1, const float* __restrict__ b1,
    const float* __restrict__ W2, const float* __restrict__ b2,
    const float* __restrict__ W3, const float* __restrict__ b3,
    const float* __restrict__ W4, const float* __restrict__ b4,
    const float* __restrict__ W5, const float* __restrict__ b5,
    const float* __restrict__ W6, const float* __restrict__ b6,
    float* __restrict__ out, int nrows)
{
    __shared__ float lds[816];
    const int tid = threadIdx.x;

#define STAGE(off, src, count) \
    for (int k = tid; k < (count); k += NTHREADS) lds[(off) + k] = (src)[k];
    STAGE(0,   W0, 84)  STAGE(84,  b0, 12)
    STAGE(96,  W1, 144) STAGE(240, b1, 12)
    STAGE(252, W2, 144) STAGE(396, b2, 12)
    STAGE(408, W3, 144) STAGE(552, b3, 12)
    STAGE(564, W4, 144) STAGE(708, b4, 12)
    STAGE(720, W5, 72)  STAGE(792, b5, 6)
    STAGE(798, W6, 6)   STAGE(804, b6, 1)
#undef STAGE
    __syncthreads();

    const long t = (long)blockIdx.x * NTHREADS + tid;
    const long row0 = t * R;
    if (row0 >= nrows) return;
    const bool full = (row0 + R) <= nrows;

    // ---- load inputs: R*7 = 28 floats = 7 float4 (base is 112B-aligned) ----
    float4 xv[7];
    if (full) {
        const float4* ip = (const float4*)(in + row0 * 7);
        #pragma unroll
        for (int k = 0; k < 7; ++k) xv[k] = ip[k];
    } else {
        float* xs = (float*)xv;
        #pragma unroll
        for (int k = 0; k < 28; ++k) xs[k] = 0.0f;
        const long nleft = nrows - row0;
        for (long r = 0; r < nleft; ++r)
            for (int i = 0; i < 7; ++i)
                ((float*)xv)[r * 7 + i] = in[(row0 + r) * 7 + i];
    }
    const float* x = (const float*)xv;  // x[r*7 + i], all indices compile-time

    float h[R][12];

    // ---- layer 0: 7 -> 12, linear ----
    {
        const float* lw = lds + 0;
        const float* lb = lds + 84;
        #pragma unroll
        for (int j = 0; j < 12; ++j) {
            const float b = lb[j];
            #pragma unroll
            for (int r = 0; r < R; ++r) h[r][j] = b;
        }
        #pragma unroll
        for (int i = 0; i < 7; ++i) {
            float w[12];
            #pragma unroll
            for (int j = 0; j < 12; ++j) w[j] = lw[i * 12 + j];
            #pragma unroll
            for (int r = 0; r < R; ++r)
                #pragma unroll
                for (int j = 0; j < 12; ++j)
                    h[r][j] = fmaf(x[r * 7 + i], w[j], h[r][j]);
        }
    }

    // ---- layers 1..4: 12 -> 12, relu ----
    #pragma unroll
    for (int li = 0; li < 4; ++li) {
        const float* lw = lds + 96 + li * 156;
        const float* lb = lds + 240 + li * 156;
        float nxt[R][12];
        #pragma unroll
        for (int j = 0; j < 12; ++j) {
            const float b = lb[j];
            #pragma unroll
            for (int r = 0; r < R; ++r) nxt[r][j] = b;
        }
        #pragma unroll
        for (int i = 0; i < 12; ++i) {
            float w[12];
            #pragma unroll
            for (int j = 0; j < 12; ++j) w[j] = lw[i * 12 + j];
            #pragma unroll
            for (int r = 0; r < R; ++r)
                #pragma unroll
                for (int j = 0; j < 12; ++j)
                    nxt[r][j] = fmaf(h[r][i], w[j], nxt[r][j]);
        }
        #pragma unroll
        for (int r = 0; r < R; ++r)
            #pragma unroll
            for (int j = 0; j < 12; ++j)
                h[r][j] = fmaxf(nxt[r][j], 0.0f);
    }

    // ---- layer 5: 12 -> 6, linear ----
    float g[R][6];
    {
        const float* lw = lds + 720;
        const float* lb = lds + 792;
        #pragma unroll
        for (int j = 0; j < 6; ++j) {
            const float b = lb[j];
            #pragma unroll
            for (int r = 0; r < R; ++r) g[r][j] = b;
        }
        #pragma unroll
        for (int i = 0; i < 12; ++i) {
            float w[6];
            #pragma unroll
            for (int j = 0; j < 6; ++j) w[j] = lw[i * 6 + j];
            #pragma unroll
            for (int r = 0; r < R; ++r)
                #pragma unroll
                for (int j = 0; j < 6; ++j)
                    g[r][j] = fmaf(h[r][i], w[j], g[r][j]);
        }
    }

    // ---- layer 6: 6 -> 1, linear ----
    float w6[6];
    #pragma unroll
    for (int i = 0; i < 6; ++i) w6[i] = lds[798 + i];
    const float b6v = lds[804];
    float o[R];
    #pragma unroll
    for (int r = 0; r < R; ++r) {
        float acc = b6v;
        #pragma unroll
        for (int i = 0; i < 6; ++i) acc = fmaf(g[r][i], w6[i], acc);
        o[r] = acc;
    }

    if (full) {
        *((float4*)(out + row0)) = make_float4(o[0], o[1], o[2], o[3]);
    } else {
        const long nleft = nrows - row0;
        for (long r = 0; r < nleft; ++r) out[row0 + r] = o[r];
    }
}

extern "C" void kernel_launch(void* const* d_in, const int* in_sizes, int n_in,
                              void* d_out, int out_size, void* d_ws, size_t ws_size,
                              hipStream_t stream) {
    const float* in = (const float*)d_in[0];
    const float* W0 = (const float*)d_in[1];  const float* b0 = (const float*)d_in[2];
    const float* W1 = (const float*)d_in[3];  const float* b1 = (const float*)d_in[4];
    const float* W2 = (const float*)d_in[5];  const float* b2 = (const float*)d_in[6];
    const float* W3 = (const float*)d_in[7];  const float* b3 = (const float*)d_in[8];
    const float* W4 = (const float*)d_in[9];  const float* b4 = (const float*)d_in[10];
    const float* W5 = (const float*)d_in[11]; const float* b5 = (const float*)d_in[12];
    const float* W6 = (const float*)d_in[13]; const float* b6 = (const float*)d_in[14];
    float* out = (float*)d_out;

    const int nrows = in_sizes[0] / 7;  // B*MS
    const long nthreads_total = ((long)nrows + R - 1) / R;
    const int blocks = (int)((nthreads_total + NTHREADS - 1) / NTHREADS);

    hipLaunchKernelGGL(mlp_kernel, dim3(blocks), dim3(NTHREADS), 0, stream,
                       in, W0, b0, W1, b1, W2, b2, W3, b3, W4, b4, W5, b5, W6, b6,
                       out, nrows);
}

// Round 2
// 128.260 us; speedup vs baseline: 1.2656x; 1.2656x over previous
//
#include <hip/hip_runtime.h>

#define R 4
#define NTHREADS 256

// LDS layout (float offsets), all weight rows 16B-aligned:
// W0  [0,84)    b0 [96,108)
// W1  [112,256) b1 [256,268)
// W2  [272,416) b2 [416,428)
// W3  [432,576) b3 [576,588)
// W4  [592,736) b4 [736,748)
// w56 [752,764) b56 764          (fused W5@W6, b5@W6+b6)

__global__ __launch_bounds__(NTHREADS, 4) void mlp_kernel(
    const float* __restrict__ in,
    const float* __restrict__ W0, const float* __restrict__ b0,
    const float* __restrict__ W1, const float* __restrict__ b1,
    const float* __restrict__ W2, const float* __restrict__ b2,
    const float* __restrict__ W3, const float* __restrict__ b3,
    const float* __restrict__ W4, const float* __restrict__ b4,
    const float* __restrict__ W5, const float* __restrict__ b5,
    const float* __restrict__ W6, const float* __restrict__ b6,
    float* __restrict__ out, int nrows)
{
    __shared__ __align__(16) float lds[768];
    const int tid = threadIdx.x;

#define STAGE(off, src, count) \
    for (int k = tid; k < (count); k += NTHREADS) lds[(off) + k] = (src)[k];
    STAGE(0,   W0, 84)  STAGE(96,  b0, 12)
    STAGE(112, W1, 144) STAGE(256, b1, 12)
    STAGE(272, W2, 144) STAGE(416, b2, 12)
    STAGE(432, W3, 144) STAGE(576, b3, 12)
    STAGE(592, W4, 144) STAGE(736, b4, 12)
#undef STAGE
    // fuse layers 5 and 6 (both linear): w56 = W5 @ W6, b56 = b5 @ W6 + b6
    if (tid < 12) {
        float acc = 0.0f;
        for (int c = 0; c < 6; ++c) acc = fmaf(W5[tid * 6 + c], W6[c], acc);
        lds[752 + tid] = acc;
    } else if (tid == 12) {
        float acc = b6[0];
        for (int c = 0; c < 6; ++c) acc = fmaf(b5[c], W6[c], acc);
        lds[764] = acc;
    }
    __syncthreads();

    const long t = (long)blockIdx.x * NTHREADS + tid;
    const long row0 = t * R;
    if (row0 >= nrows) return;
    const bool full = (row0 + R) <= nrows;

    // ---- load inputs: R*7 = 28 floats = 7 float4 (base 112B-aligned) ----
    float xs[28];
    if (full) {
        const float4* ip = (const float4*)(in + row0 * 7);
        float4 q;
        q = ip[0]; xs[0]=q.x;  xs[1]=q.y;  xs[2]=q.z;  xs[3]=q.w;
        q = ip[1]; xs[4]=q.x;  xs[5]=q.y;  xs[6]=q.z;  xs[7]=q.w;
        q = ip[2]; xs[8]=q.x;  xs[9]=q.y;  xs[10]=q.z; xs[11]=q.w;
        q = ip[3]; xs[12]=q.x; xs[13]=q.y; xs[14]=q.z; xs[15]=q.w;
        q = ip[4]; xs[16]=q.x; xs[17]=q.y; xs[18]=q.z; xs[19]=q.w;
        q = ip[5]; xs[20]=q.x; xs[21]=q.y; xs[22]=q.z; xs[23]=q.w;
        q = ip[6]; xs[24]=q.x; xs[25]=q.y; xs[26]=q.z; xs[27]=q.w;
    } else {
        #pragma unroll
        for (int r = 0; r < R; ++r)
            #pragma unroll
            for (int i = 0; i < 7; ++i)
                xs[r * 7 + i] = ((row0 + r) < nrows) ? in[(row0 + r) * 7 + i] : 0.0f;
    }

#define LOADW12(dst, baseptr) { \
    const float4* _p = (const float4*)(baseptr); \
    float4 _a = _p[0], _b = _p[1], _c = _p[2]; \
    dst[0]=_a.x; dst[1]=_a.y; dst[2]=_a.z;  dst[3]=_a.w; \
    dst[4]=_b.x; dst[5]=_b.y; dst[6]=_b.z;  dst[7]=_b.w; \
    dst[8]=_c.x; dst[9]=_c.y; dst[10]=_c.z; dst[11]=_c.w; }

    float h[R][12];

    // ---- layer 0: 7 -> 12, linear (i=0 peeled to fold bias) ----
    {
        float bb[12]; LOADW12(bb, lds + 96);
        float w[12];  LOADW12(w, lds + 0);
        #pragma unroll
        for (int r = 0; r < R; ++r)
            #pragma unroll
            for (int j = 0; j < 12; ++j)
                h[r][j] = fmaf(xs[r * 7 + 0], w[j], bb[j]);
        #pragma unroll
        for (int i = 1; i < 7; ++i) {
            LOADW12(w, lds + i * 12);
            #pragma unroll
            for (int r = 0; r < R; ++r)
                #pragma unroll
                for (int j = 0; j < 12; ++j)
                    h[r][j] = fmaf(xs[r * 7 + i], w[j], h[r][j]);
        }
    }

    // ---- layers 1..4: 12 -> 12, relu ----
    constexpr int WOFF[4] = {112, 272, 432, 592};
    constexpr int BOFF[4] = {256, 416, 576, 736};
    #pragma unroll
    for (int li = 0; li < 4; ++li) {
        float nxt[R][12];
        {
            float bb[12]; LOADW12(bb, lds + BOFF[li]);
            float w[12];  LOADW12(w, lds + WOFF[li]);
            #pragma unroll
            for (int r = 0; r < R; ++r)
                #pragma unroll
                for (int j = 0; j < 12; ++j)
                    nxt[r][j] = fmaf(h[r][0], w[j], bb[j]);
        }
        #pragma unroll
        for (int i = 1; i < 12; ++i) {
            float w[12]; LOADW12(w, lds + WOFF[li] + i * 12);
            #pragma unroll
            for (int r = 0; r < R; ++r)
                #pragma unroll
                for (int j = 0; j < 12; ++j)
                    nxt[r][j] = fmaf(h[r][i], w[j], nxt[r][j]);
        }
        #pragma unroll
        for (int r = 0; r < R; ++r)
            #pragma unroll
            for (int j = 0; j < 12; ++j)
                h[r][j] = fmaxf(nxt[r][j], 0.0f);
    }

    // ---- fused layers 5+6: 12 -> 1, linear ----
    float w56[12]; LOADW12(w56, lds + 752);
    const float b56 = lds[764];
    float o[R];
    #pragma unroll
    for (int r = 0; r < R; ++r) {
        float acc = fmaf(h[r][0], w56[0], b56);
        #pragma unroll
        for (int i = 1; i < 12; ++i) acc = fmaf(h[r][i], w56[i], acc);
        o[r] = acc;
    }

    if (full) {
        *((float4*)(out + row0)) = make_float4(o[0], o[1], o[2], o[3]);
    } else {
        #pragma unroll
        for (int r = 0; r < R; ++r)
            if ((row0 + r) < nrows) out[row0 + r] = o[r];
    }
#undef LOADW12
}

extern "C" void kernel_launch(void* const* d_in, const int* in_sizes, int n_in,
                              void* d_out, int out_size, void* d_ws, size_t ws_size,
                              hipStream_t stream) {
    const float* in = (const float*)d_in[0];
    const float* W0 = (const float*)d_in[1];  const float* b0 = (const float*)d_in[2];
    const float* W1 = (const float*)d_in[3];  const float* b1 = (const float*)d_in[4];
    const float* W2 = (const float*)d_in[5];  const float* b2 = (const float*)d_in[6];
    const float* W3 = (const float*)d_in[7];  const float* b3 = (const float*)d_in[8];
    const float* W4 = (const float*)d_in[9];  const float* b4 = (const float*)d_in[10];
    const float* W5 = (const float*)d_in[11]; const float* b5 = (const float*)d_in[12];
    const float* W6 = (const float*)d_in[13]; const float* b6 = (const float*)d_in[14];
    float* out = (float*)d_out;

    const int nrows = in_sizes[0] / 7;  // B*MS
    const long nthreads_total = ((long)nrows + R - 1) / R;
    const int blocks = (int)((nthreads_total + NTHREADS - 1) / NTHREADS);

    hipLaunchKernelGGL(mlp_kernel, dim3(blocks), dim3(NTHREADS), 0, stream,
                       in, W0, b0, W1, b1, W2, b2, W3, b3, W4, b4, W5, b5, W6, b6,
                       out, nrows);
}